// Round 15
// baseline (97.836 us; speedup 1.0000x reference)
//
#include <hip/hip_runtime.h>
#include <hip/hip_bf16.h>

#define F_   512
#define FF_  (512 * 512)
#define C_   128

typedef __attribute__((ext_vector_type(4))) float f32x4;
typedef __attribute__((ext_vector_type(8))) short s16x8;
typedef __attribute__((ext_vector_type(4))) unsigned short u16x4;

__device__ __forceinline__ unsigned short f2bf(float f) {
    union { __hip_bfloat16 h; unsigned short u; } c;
    c.h = __float2bfloat16(f);
    return c.u;
}

__device__ __forceinline__ s16x8 pack8(f32x4 lo, f32x4 hi) {
    s16x8 r;
    r[0] = (short)f2bf(lo[0]); r[1] = (short)f2bf(lo[1]);
    r[2] = (short)f2bf(lo[2]); r[3] = (short)f2bf(lo[3]);
    r[4] = (short)f2bf(hi[0]); r[5] = (short)f2bf(hi[1]);
    r[6] = (short)f2bf(hi[2]); r[7] = (short)f2bf(hi[3]);
    return r;
}

#define GLDS16(gp, lp)                                                         \
    __builtin_amdgcn_global_load_lds(                                          \
        (const __attribute__((address_space(1))) void*)(gp),                   \
        (__attribute__((address_space(3))) void*)(lp), 16, 0, 0)

// ---------------------------------------------------------------------------
// Kernel 0: pre-pack phi -> per-(bt,kk,lane) bf16 MFMA B-fragments.
// ---------------------------------------------------------------------------
__global__ __launch_bounds__(256) void k0_prepack(
    const float* __restrict__ phi, unsigned short* __restrict__ phiP)
{
    const int t = threadIdx.x;
#pragma unroll
    for (int j = 0; j < 4; ++j) {
        int e = (j << 8) + t;               // 0..1023
        int lane = e & 63, mk = e >> 6;
        int m = mk >> 2, kk = mk & 3;
        int brow = lane & 15, quad = lane >> 4;
        const float* p = phi + ((m << 4) + brow) * C_ + kk * 32 + (quad << 3);
        s16x8 v = pack8(*(const f32x4*)p, *(const f32x4*)(p + 4));
        *(s16x8*)&phiP[e << 3] = v;
    }
}

// ---------------------------------------------------------------------------
// Kernel 1 v16: v9 (operand-swapped, wave-private, barrier-free) at 2x the
// occupancy. Staged granule halved to 4KB (16 rows x 256B half-K slice);
// 16 iters (8 ct x 2 half), acc accumulates across the half pair, store on
// the odd half. Per-wave LDS 8KB -> block 32KB -> 16 waves/CU (vs v9's 8).
// Swizzle: source fetches logical unit (lane&15)^(row&7) -> slot u^(row&7);
// ds_read XORs the same. Exact counted vmcnt for the 4-load/4-store
// interleave: h=0 ->4, even ->8, odd ->4, last ->0.
// Blocks 0..511 compute; 512..639 bias rows.
// ---------------------------------------------------------------------------
__global__ __launch_bounds__(256, 4) void k1_params(
    const unsigned short* __restrict__ phiP, const float* __restrict__ Wc,
    const float* __restrict__ bc, unsigned short* __restrict__ wT,
    float* __restrict__ biasWS, const float* __restrict__ phi)
{
    const int blk = blockIdx.x;
    const int tid = threadIdx.x;

    if (blk >= 512) {                       // ---- bias part ----
        int g = ((blk - 512) << 8) + tid;   // 0..32767
        int k = g >> 6, b = g & 63;
        const f32x4* w4 = (const f32x4*)(Wc + (size_t)(FF_ + k) * C_);
        const f32x4* p4 = (const f32x4*)(phi + b * C_);
        float acc = bc[FF_ + k];
#pragma unroll
        for (int c = 0; c < 32; ++c) {
            f32x4 a = w4[c], q = p4[c];
            acc += a[0]*q[0] + a[1]*q[1] + a[2]*q[2] + a[3]*q[3];
        }
        biasWS[(b << 9) + k] = acc;
        return;
    }

    __shared__ __align__(16) char stg[4][2][4096];   // wave-private dbuf, 32 KB

    const int lane = tid & 63, wave = tid >> 6, quad = lane >> 4;
    const int w  = (blk << 2) + wave;       // global wave id 0..2047
    const int i0 = (w & 31) << 4;           // 32 i-tiles of 16
    const int k0 = (w >> 5) << 3;           // 64 k-octets

    // ---- B-fragments (phi) from phiP: 16 contiguous 1KB loads (64 VGPR)
    s16x8 bfrP[4][4];
#pragma unroll
    for (int mk = 0; mk < 16; ++mk)
        bfrP[mk >> 2][mk & 3] = *(const s16x8*)&phiP[((mk << 6) + lane) << 3];

    // ---- bias regs: bias[rr][ct] = bc[(i0+quad*4+rr)*512 + k0+ct]
    f32x4 biasv[4][2];
#pragma unroll
    for (int rr = 0; rr < 4; ++rr) {
        const float* p = bc + (i0 + (quad << 2) + rr) * F_ + k0;
        biasv[rr][0] = *(const f32x4*)p;
        biasv[rr][1] = *(const f32x4*)(p + 4);
    }

    // ---- keep bits: bit(ct*4+rr) = d_i >= d_k ; per-ct wave-uniform skip
    unsigned keepm = 0;
#pragma unroll
    for (int ct = 0; ct < 8; ++ct) {
        int dk = (k0 + ct) % 63;
#pragma unroll
        for (int rr = 0; rr < 4; ++rr) {
            int di = (i0 + (quad << 2) + rr) % 63;
            if (di >= dk) keepm |= 1u << ((ct << 2) + rr);
        }
    }
    int maxd = i0 % 63 + 15; maxd = maxd > 62 ? 62 : maxd;
    unsigned skipm = 0;
#pragma unroll
    for (int ct = 0; ct < 8; ++ct)
        if (((k0 + ct) % 63) > maxd) skipm |= 1u << ct;

    char* const stw0 = stg[wave][0];
    char* const stw1 = stg[wave][1];
    const int lq = lane >> 4;               // row sub-index within inst

    // STAGE(h): 4 glds x 1KB; inst j covers rows 4j..4j+3 (half-K slices).
    // Source fetches logical unit (lane&15)^(row&7); dest linear (rule 21).
    auto STAGE = [&](int h, char* dst) {
        const int ct = h >> 1, half = h & 1;
        const bool sk = (skipm >> ct) & 1;
        const int k = k0 + ct;
#pragma unroll
        for (int j = 0; j < 4; ++j) {
            int row = (j << 2) + lq;
            int isrc = sk ? i0 : (i0 + row);
            const char* src = (const char*)(Wc + ((size_t)(isrc * F_ + k)) * C_)
                            + (half << 8)
                            + ((((lane & 15) ^ (row & 7)) << 4));
            GLDS16(src, dst + (j << 10));   // +lane*16 -> row*256 + slot*16
        }
    };

    STAGE(0, stw0);

    f32x4 acc[4];

#pragma unroll
    for (int h = 0; h < 16; ++h) {
        if (h < 15) STAGE(h + 1, ((h + 1) & 1) ? stw1 : stw0);

        if      (h == 0)  asm volatile("s_waitcnt vmcnt(4)" ::: "memory");
        else if (h == 15) asm volatile("s_waitcnt vmcnt(0)" ::: "memory");
        else if (h & 1)   asm volatile("s_waitcnt vmcnt(4)" ::: "memory");
        else              asm volatile("s_waitcnt vmcnt(8)" ::: "memory");
        __builtin_amdgcn_sched_barrier(0);

        const int ct = h >> 1, half = h & 1;
        const bool sk = (skipm >> ct) & 1;

        if (half == 0)
#pragma unroll
            for (int bt = 0; bt < 4; ++bt) acc[bt] = (f32x4){0.f, 0.f, 0.f, 0.f};

        if (!sk) {
            char* bufc = (h & 1) ? stw1 : stw0;
            const int r = lane & 15;
            const int rbase = r << 8;                // row*256
            const int rx = r & 7;
#pragma unroll
            for (int kl = 0; kl < 2; ++kl) {
                int u0 = (kl << 3) + (quad << 1);
                f32x4 lo = *(const f32x4*)(bufc + rbase + ((u0 ^ rx) << 4));
                f32x4 hi = *(const f32x4*)(bufc + rbase + (((u0 + 1) ^ rx) << 4));
                s16x8 aW = pack8(lo, hi);
                const int kkg = (half << 1) + kl;
#pragma unroll
                for (int bt = 0; bt < 4; ++bt)
                    acc[bt] = __builtin_amdgcn_mfma_f32_16x16x32_bf16(
                        aW, bfrP[bt][kkg], acc[bt], 0, 0, 0);
            }
        }

        if (half == 1) {     // ---- direct store (v9 pattern) ----
            const int k = k0 + ct;
#pragma unroll
            for (int bt = 0; bt < 4; ++bt) {
                u16x4 v;
#pragma unroll
                for (int rr = 0; rr < 4; ++rr) {
                    bool kp = (!sk) && ((keepm >> ((ct << 2) + rr)) & 1);
                    float bv = (ct < 4) ? biasv[rr][0][ct] : biasv[rr][1][ct - 4];
                    v[rr] = kp ? f2bf(acc[bt][rr] + bv) : (unsigned short)0;
                }
                int b = (bt << 4) + (lane & 15);
                *(u16x4*)&wT[(((size_t)((b << 9) + k)) << 9) + i0 + (quad << 2)] = v;
            }
        }
    }
}

// ---------------------------------------------------------------------------
// Kernel 2 (unchanged): two chained GEMMs vs wT + bias, residual epilogue.
// ---------------------------------------------------------------------------
#define SMEM_BOFF 66560           // 64*1040
#define CHUNK_B   32768
#define SMEM_TOT  (66560 + 2 * 32768)   // 132096

__global__ __launch_bounds__(512) void k2_apply(
    const float* __restrict__ X, const unsigned short* __restrict__ wT,
    const float* __restrict__ biasWS, float* __restrict__ out)
{
    extern __shared__ char smem[];
    unsigned short* A_lds = (unsigned short*)smem;

    const int blk = blockIdx.x;
    const int sw  = ((blk & 7) << 5) + (blk >> 3);   // XCD swizzle
    const int b   = sw >> 2;
    const int n0  = (sw & 3) << 6;

    const int tid = threadIdx.x, lane = tid & 63, wave = tid >> 6;
    const int wn = wave >> 2, wk = wave & 3;

    const float* Xb = X + (((size_t)(b * 256 + n0)) << 9);
    float*       Ob = out + (((size_t)(b * 256 + n0)) << 9);
    const unsigned short* wTb = wT + ((size_t)b << 18);

    float biasr[8];
#pragma unroll
    for (int nt = 0; nt < 8; ++nt)
        biasr[nt] = biasWS[(b << 9) + (wk << 7) + (nt << 4) + (lane & 15)];

    {
        const f32x4* X4 = (const f32x4*)Xb;
#pragma unroll
        for (int j = 0; j < 16; ++j) {
            int f = (j << 9) + tid;
            int row = f >> 7, c4 = f & 127;
            f32x4 v = X4[f];
            u16x4 h;
#pragma unroll
            for (int e = 0; e < 4; ++e) h[e] = f2bf(fmaxf(v[e], 0.f));
            *(u16x4*)&A_lds[row * 520 + (c4 << 2)] = h;
        }
    }

    const int srcslot = ((lane & 3) ^ ((lane >> 3) & 3)) << 3;

    f32x4 acc[2][8];

    for (int phase = 0; phase < 2; ++phase) {
#pragma unroll
        for (int mt = 0; mt < 2; ++mt)
#pragma unroll
            for (int nt = 0; nt < 8; ++nt) acc[mt][nt] = (f32x4){0.f, 0.f, 0.f, 0.f};

#pragma unroll
        for (int g = 0; g < 4; ++g) {
            int krow = (wave << 6) + (g << 4) + (lane >> 2);
            const unsigned short* src = wTb + ((size_t)krow << 9) + srcslot;
            char* lp = smem + SMEM_BOFF + (((wave << 6) + (g << 4)) << 6);
            GLDS16(src, lp);
        }
        asm volatile("s_waitcnt vmcnt(0)" ::: "memory");
        __syncthreads();

        for (int c = 0; c < 16; ++c) {
            const int cur = c & 1;
            if (c < 15) {
                const int i0n = (c + 1) << 5;
#pragma unroll
                for (int g = 0; g < 4; ++g) {
                    int krow = (wave << 6) + (g << 4) + (lane >> 2);
                    const unsigned short* src = wTb + ((size_t)krow << 9) + i0n + srcslot;
                    char* lp = smem + SMEM_BOFF + (cur ^ 1) * CHUNK_B
                             + (((wave << 6) + (g << 4)) << 6);
                    GLDS16(src, lp);
                }
            }
            const int i0c = c << 5;
            s16x8 afr[2];
#pragma unroll
            for (int mt = 0; mt < 2; ++mt) {
                int n = (wn << 5) + (mt << 4) + (lane & 15);
                afr[mt] = *(const s16x8*)&A_lds[n * 520 + i0c + ((lane >> 4) << 3)];
            }
            const unsigned short* Bb =
                (const unsigned short*)(smem + SMEM_BOFF + cur * CHUNK_B);
#pragma unroll
            for (int nt = 0; nt < 8; ++nt) {
                int k = (wk << 7) + (nt << 4) + (lane & 15);
                int slot = (((lane >> 4) ^ ((k >> 1) & 3)) << 3);
                s16x8 bfr = *(const s16x8*)&Bb[(k << 5) + slot];
#pragma unroll
                for (int mt = 0; mt < 2; ++mt)
                    acc[mt][nt] = __builtin_amdgcn_mfma_f32_16x16x32_bf16(
                        afr[mt], bfr, acc[mt][nt], 0, 0, 0);
            }
            asm volatile("s_waitcnt vmcnt(0)" ::: "memory");
            __syncthreads();
        }

        if (phase == 0) {
#pragma unroll
            for (int mt = 0; mt < 2; ++mt)
#pragma unroll
                for (int nt = 0; nt < 8; ++nt) {
                    int k = (wk << 7) + (nt << 4) + (lane & 15);
#pragma unroll
                    for (int r = 0; r < 4; ++r) {
                        int n = (wn << 5) + (mt << 4) + ((lane >> 4) << 2) + r;
                        A_lds[n * 520 + k] =
                            f2bf(fmaxf(acc[mt][nt][r] + biasr[nt], 0.f));
                    }
                }
            __syncthreads();
        }
    }

#pragma unroll
    for (int mt = 0; mt < 2; ++mt)
#pragma unroll
        for (int nt = 0; nt < 8; ++nt) {
            int k = (wk << 7) + (nt << 4) + (lane & 15);
#pragma unroll
            for (int r = 0; r < 4; ++r) {
                int n = (wn << 5) + (mt << 4) + ((lane >> 4) << 2) + r;
                size_t off = ((size_t)n << 9) + k;
                Ob[off] = Xb[off] + acc[mt][nt][r] + biasr[nt];
            }
        }
}

extern "C" void kernel_launch(void* const* d_in, const int* in_sizes, int n_in,
                              void* d_out, int out_size, void* d_ws, size_t ws_size,
                              hipStream_t stream) {
    const float* inputs = (const float*)d_in[0];
    const float* phi    = (const float*)d_in[1];
    const float* Wc     = (const float*)d_in[2];
    const float* bc     = (const float*)d_in[3];
    float* out = (float*)d_out;

    unsigned short* wT = (unsigned short*)d_ws;                          // 32 MiB
    float* biasWS = (float*)((char*)d_ws + (size_t)64 * 512 * 512 * 2);  // 128 KiB
    unsigned short* phiP =
        (unsigned short*)((char*)d_ws + (size_t)64 * 512 * 512 * 2 + 64 * 512 * 4);

    hipLaunchKernelGGL(k0_prepack, dim3(1), dim3(256), 0, stream, phi, phiP);

    hipLaunchKernelGGL(k1_params, dim3(640), dim3(256), 0, stream,
                       phiP, Wc, bc, wT, biasWS, phi);

    hipFuncSetAttribute((const void*)k2_apply,
                        hipFuncAttributeMaxDynamicSharedMemorySize, SMEM_TOT);
    hipLaunchKernelGGL(k2_apply, dim3(256), dim3(512), SMEM_TOT, stream,
                       inputs, wT, biasWS, out);
}